// Round 14
// baseline (170.720 us; speedup 1.0000x reference)
//
#include <hip/hip_runtime.h>
#include <hip/hip_bf16.h>
#include <cstdint>
#include <cstddef>

// Shapes (compile-time)
#define Bq 4
#define Nseq 1024
#define Dm 1024
#define Hh 16
#define HDd 64
#define FFd 2048
#define Mrows 4096  // B*N

typedef __attribute__((ext_vector_type(8))) short bf16x8;   // 8 bf16 = 4 VGPRs
typedef __attribute__((ext_vector_type(4))) float f32x4;
typedef __attribute__((ext_vector_type(16))) float f32x16;

__device__ __forceinline__ void gl_lds16(const void* g, void* l) {
  // async global->LDS, 16B per lane; LDS dest = wave-uniform base + lane*16
  __builtin_amdgcn_global_load_lds(
      (const __attribute__((address_space(1))) unsigned int*)g,
      (__attribute__((address_space(3))) unsigned int*)l, 16, 0, 0);
}

__device__ __forceinline__ unsigned short f2b(float f) {
  union { __hip_bfloat16 h; unsigned short u; } cv;
  cv.h = __float2bfloat16(f);
  return cv.u;
}

__device__ __forceinline__ unsigned cvt_pk_bf16(float a, float b) {
  unsigned r;
  asm("v_cvt_pk_bf16_f32 %0, %1, %2" : "=v"(r) : "v"(a), "v"(b));
  return r;  // low16 = bf16(a), high16 = bf16(b)
}

__device__ __forceinline__ void pl32_swap(unsigned& a, unsigned& b) {
  asm("v_permlane32_swap_b32 %0, %1" : "+v"(a), "+v"(b));
}

// XCD-chunked swizzle (T1): dispatch index d -> logical block l such that each
// XCD (d%8) owns a CONTIGUOUS logical chunk. Requires nwg % 8 == 0.
__device__ __forceinline__ int xcd_swz(int d, int nwg) {
  return (d & 7) * (nwg >> 3) + (d >> 3);
}

// ---------------- prep kernel: 4 weight transposes + LN1 fused in one dispatch
__device__ __forceinline__ void tr_tile(const float* __restrict__ src,
                                        __hip_bfloat16* __restrict__ dst,
                                        int K, int Ncols, int n0, int k0,
                                        int tid) {
  __shared__ float tile[32][33];
  const int tx = tid & 31, ty = tid >> 5;  // ty 0..7
#pragma unroll
  for (int i = 0; i < 32; i += 8)
    tile[ty + i][tx] = src[(size_t)(k0 + ty + i) * Ncols + n0 + tx];
  __syncthreads();
#pragma unroll
  for (int i = 0; i < 32; i += 8)
    dst[(size_t)(n0 + ty + i) * K + k0 + tx] = __float2bfloat16(tile[tx][ty + i]);
}

__global__ __launch_bounds__(256) void prep_kernel(
    const float* __restrict__ qkv_w, __hip_bfloat16* __restrict__ wqkv_t,
    const float* __restrict__ out_w, __hip_bfloat16* __restrict__ wout_t,
    const float* __restrict__ w1, __hip_bfloat16* __restrict__ w1_t,
    const float* __restrict__ w2, __hip_bfloat16* __restrict__ w2_t,
    const float* __restrict__ x, const float* __restrict__ ln1_g,
    const float* __restrict__ ln1_b, __hip_bfloat16* __restrict__ xn) {
  const int id = blockIdx.x, tid = threadIdx.x;
  if (id < 3072) {
    tr_tile(qkv_w, wqkv_t, Dm, 3 * Dm, (id % 96) * 32, (id / 96) * 32, tid);
  } else if (id < 4096) {
    const int i2 = id - 3072;
    tr_tile(out_w, wout_t, Dm, Dm, (i2 % 32) * 32, (i2 / 32) * 32, tid);
  } else if (id < 6144) {
    const int i2 = id - 4096;
    tr_tile(w1, w1_t, Dm, FFd, (i2 % 64) * 32, (i2 / 64) * 32, tid);
  } else if (id < 8192) {
    const int i2 = id - 6144;
    tr_tile(w2, w2_t, FFd, Dm, (i2 % 32) * 32, (i2 / 32) * 32, tid);
  } else {
    const int row = id - 8192;
    const float4 v = reinterpret_cast<const float4*>(x + (size_t)row * Dm)[tid];
    float s1 = v.x + v.y + v.z + v.w;
    float s2 = v.x * v.x + v.y * v.y + v.z * v.z + v.w * v.w;
#pragma unroll
    for (int m = 1; m < 64; m <<= 1) {
      s1 += __shfl_xor(s1, m);
      s2 += __shfl_xor(s2, m);
    }
    __shared__ float a1[4], a2[4];
    const int wv = tid >> 6;
    if ((tid & 63) == 0) { a1[wv] = s1; a2[wv] = s2; }
    __syncthreads();
    s1 = a1[0] + a1[1] + a1[2] + a1[3];
    s2 = a2[0] + a2[1] + a2[2] + a2[3];
    const float mu = s1 * (1.f / Dm);
    const float rs = rsqrtf(s2 * (1.f / Dm) - mu * mu + 1e-5f);
    const float4 g4 = reinterpret_cast<const float4*>(ln1_g)[tid];
    const float4 b4 = reinterpret_cast<const float4*>(ln1_b)[tid];
    ushort4 o;
    o.x = f2b((v.x - mu) * rs * g4.x + b4.x);
    o.y = f2b((v.y - mu) * rs * g4.y + b4.y);
    o.z = f2b((v.z - mu) * rs * g4.z + b4.z);
    o.w = f2b((v.w - mu) * rs * g4.w + b4.w);
    reinterpret_cast<ushort4*>(xn + (size_t)row * Dm)[tid] = o;
  }
}

// ---------------- layernorm over bf16 input: [4096][1024] row -> bf16 out (LN2)
__global__ __launch_bounds__(256) void ln_bf16_kernel(
    const __hip_bfloat16* __restrict__ xb, const float* __restrict__ gw,
    const float* __restrict__ bw, __hip_bfloat16* __restrict__ out) {
  const int row = blockIdx.x;
  const ushort4 u = reinterpret_cast<const ushort4*>(xb + (size_t)row * Dm)[threadIdx.x];
  union { __hip_bfloat16 h; unsigned short s; } c0{{}}, c1{{}}, c2{{}}, c3{{}};
  c0.s = u.x; c1.s = u.y; c2.s = u.z; c3.s = u.w;
  float vx = __bfloat162float(c0.h), vy = __bfloat162float(c1.h);
  float vz = __bfloat162float(c2.h), vw = __bfloat162float(c3.h);
  float s1 = vx + vy + vz + vw;
  float s2 = vx * vx + vy * vy + vz * vz + vw * vw;
#pragma unroll
  for (int m = 1; m < 64; m <<= 1) {
    s1 += __shfl_xor(s1, m);
    s2 += __shfl_xor(s2, m);
  }
  __shared__ float a1[4], a2[4];
  const int wv = threadIdx.x >> 6;
  if ((threadIdx.x & 63) == 0) { a1[wv] = s1; a2[wv] = s2; }
  __syncthreads();
  s1 = a1[0] + a1[1] + a1[2] + a1[3];
  s2 = a2[0] + a2[1] + a2[2] + a2[3];
  const float mu = s1 * (1.f / Dm);
  const float rs = rsqrtf(s2 * (1.f / Dm) - mu * mu + 1e-5f);
  const float4 g4 = reinterpret_cast<const float4*>(gw)[threadIdx.x];
  const float4 b4 = reinterpret_cast<const float4*>(bw)[threadIdx.x];
  ushort4 o;
  o.x = f2b((vx - mu) * rs * g4.x + b4.x);
  o.y = f2b((vy - mu) * rs * g4.y + b4.y);
  o.z = f2b((vz - mu) * rs * g4.z + b4.z);
  o.w = f2b((vw - mu) * rs * g4.w + b4.w);
  reinterpret_cast<ushort4*>(out + (size_t)row * Dm)[threadIdx.x] = o;
}

// ---------------- QKV GEMM v6: 128x128 tile, BK=32, DOUBLE-buffered (32 KB
// LDS total, 3 blocks/CU), 32x32x16 MFMA, COUNTED vmcnt (T4): raw s_barrier +
// s_waitcnt vmcnt(4) retiring only the OLDER tile's 4 loads -- never 0 in the
// loop. Staging/swizzle geometry = R8-verified BK=32 layout.
// Count proof: 4 global_load_lds per wave per tile; at the wait <=8
// outstanding (4 for tile kt+1 from last iter + 4 for kt+2 just issued);
// vmcnt(4) retires the older 4 => tile kt+1 resident; barrier publishes.
__global__ __launch_bounds__(256, 3) void gemm_qkv(
    const __hip_bfloat16* __restrict__ A, const __hip_bfloat16* __restrict__ BT,
    const float* __restrict__ bias,
    __hip_bfloat16* __restrict__ qb, __hip_bfloat16* __restrict__ kb,
    __hip_bfloat16* __restrict__ vtb, int Ndim, int Kdim) {
  __shared__ alignas(16) __hip_bfloat16 As[2][128 * 32];  // 2 x 8 KB
  __shared__ alignas(16) __hip_bfloat16 Bs[2][128 * 32];  // 2 x 8 KB
  const int tid = threadIdx.x;
  const int wv = tid >> 6, ln = tid & 63;
  const int wm = wv >> 1, wn = wv & 1;
  const int lq = ln & 31, hl = ln >> 5;
  const int gx = gridDim.x;
  const int l = xcd_swz(blockIdx.x + gx * blockIdx.y, gx * gridDim.y);
  const int rowBase = (l / gx) * 128;
  const int colBase = (l % gx) * 128;

  // R8-verified BK=32 staging: row = 32 bf16 = 64B = 4 x 16B chunks; wave
  // round = 1KB = 16 rows; block round = 4KB = 64 rows; 2 rounds per operand.
  const int st_row = wv * 16 + (ln >> 2);            // row within 64-row round
  const int st_lc  = (ln & 3) ^ ((ln >> 3) & 3);     // swizzled chunk fetched
  const int rsw    = (lq >> 1) & 3;                  // read-side row swizzle

  f32x16 acc[2][2];
#pragma unroll
  for (int i = 0; i < 2; ++i)
#pragma unroll
    for (int j = 0; j < 2; ++j) acc[i][j] = {};

  auto stage = [&](int buf, int k0) {
#pragma unroll
    for (int r = 0; r < 2; ++r) {
      gl_lds16(A + (size_t)(rowBase + r * 64 + st_row) * Kdim + k0 + st_lc * 8,
               (char*)&As[buf][0] + r * 4096 + wv * 1024);
      gl_lds16(BT + (size_t)(colBase + r * 64 + st_row) * Kdim + k0 + st_lc * 8,
               (char*)&Bs[buf][0] + r * 4096 + wv * 1024);
    }
  };

  const int nt = Kdim >> 5;  // 32 tiles
  // prologue: tiles 0,1 issued; wait only tile 0's 4 loads (leave tile 1's 4)
  stage(0, 0);
  stage(1, 32);
  asm volatile("s_waitcnt vmcnt(4)" ::: "memory");
  __builtin_amdgcn_s_barrier();

  for (int kt = 0; kt < nt; ++kt) {
    const char* Ap = (const char*)&As[kt & 1][0];
    const char* Bp = (const char*)&Bs[kt & 1][0];
#pragma unroll
    for (int ks = 0; ks < 2; ++ks) {
      bf16x8 af[2], bfr[2];
#pragma unroll
      for (int i = 0; i < 2; ++i)
        af[i] = *reinterpret_cast<const bf16x8*>(
            Ap + (wm * 64 + i * 32 + lq) * 64 + (((ks * 2 + hl) ^ rsw) * 16));
#pragma unroll
      for (int j = 0; j < 2; ++j)
        bfr[j] = *reinterpret_cast<const bf16x8*>(
            Bp + (wn * 64 + j * 32 + lq) * 64 + (((ks * 2 + hl) ^ rsw) * 16));
#pragma unroll
      for (int i = 0; i < 2; ++i)
#pragma unroll
        for (int j = 0; j < 2; ++j)
          acc[i][j] = __builtin_amdgcn_mfma_f32_32x32x16_bf16(af[i], bfr[j], acc[i][j], 0, 0, 0);
    }
    if (kt + 1 < nt) {
      __builtin_amdgcn_s_barrier();  // all waves done reading buf[kt&1]
      if (kt + 2 < nt) {
        stage(kt & 1, (kt + 2) << 5);               // overwrite freed buffer
        asm volatile("s_waitcnt vmcnt(4)" ::: "memory");  // retire kt+1's loads
      } else {
        asm volatile("s_waitcnt vmcnt(0)" ::: "memory");  // no new issue: drain
      }
      __builtin_amdgcn_s_barrier();  // tile kt+1 resident for all waves
    }
  }

  // epilogue: 32x32 C/D layout: col = lq, row = (r&3) + 8*(r>>2) + 4*hl
#pragma unroll
  for (int i = 0; i < 2; ++i) {
#pragma unroll
    for (int j = 0; j < 2; ++j) {
      const int gc = colBase + wn * 64 + j * 32 + lq;
      const float bv = bias[gc];
#pragma unroll
      for (int r = 0; r < 16; ++r) {
        const int gr = rowBase + wm * 64 + i * 32 + (r & 3) + 8 * (r >> 2) + 4 * hl;
        float v = acc[i][j][r] + bv;
        const int which = gc >> 10;
        const int dcol = gc & 1023;
        const int h = dcol >> 6, hd = dcol & 63;
        const int b = gr >> 10, n = gr & 1023;
        const size_t bh = (size_t)(b * Hh + h);
        if (which == 0)
          qb[(bh * Nseq + n) * HDd + hd] = __float2bfloat16(v * 0.125f);
        else if (which == 1)
          kb[(bh * Nseq + n) * HDd + hd] = __float2bfloat16(v);
        else
          vtb[(bh * HDd + hd) * Nseq + n] = __float2bfloat16(v);
      }
    }
  }
}

// ---------------- skinny GEMM: 64x128 tile, 4 waves 2M x 2N, per-wave 32x64,
// BK=64 single-buffer, 24 KB LDS, XCD-chunked swizzle. (Control: unchanged.)
// EPI 1: bf16 out = bf16(acc + bias + resF)   (outproj residual; x1 bf16)
// EPI 2: bf16 out = gelu(acc + bias)
// EPI 3: f32 out = acc + bias + float(resB)   (FFN2 residual from bf16 x1)
template <int EPI>
__global__ __launch_bounds__(256, 4) void gemm_sk(
    const __hip_bfloat16* __restrict__ A, const __hip_bfloat16* __restrict__ BT,
    const float* __restrict__ bias, const float* __restrict__ resF,
    const __hip_bfloat16* __restrict__ resB,
    float* __restrict__ outF, __hip_bfloat16* __restrict__ outB,
    int Ndim, int Kdim) {
  __shared__ alignas(16) __hip_bfloat16 As[64 * 64];    // 8 KB
  __shared__ alignas(16) __hip_bfloat16 Bs[128 * 64];   // 16 KB
  const int tid = threadIdx.x;
  const int wv = tid >> 6, ln = tid & 63;
  const int wm = wv >> 1, wn = wv & 1;
  const int lq = ln & 31, hl = ln >> 5;
  const int gx = gridDim.x;
  const int l = xcd_swz(blockIdx.x + gx * blockIdx.y, gx * gridDim.y);
  const int rowBase = (l / gx) * 64;
  const int colBase = (l % gx) * 128;

  const int st_row = tid >> 3;
  const int st_c = (tid & 7) ^ (st_row & 7);

  f32x16 acc[2];
  acc[0] = {}; acc[1] = {};

  auto stage = [&](int k0) {
#pragma unroll
    for (int r = 0; r < 2; ++r)
      gl_lds16(A + (size_t)(rowBase + r * 32 + st_row) * Kdim + k0 + st_c * 8,
               (char*)As + r * 4096 + wv * 1024);
#pragma unroll
    for (int r = 0; r < 4; ++r)
      gl_lds16(BT + (size_t)(colBase + r * 32 + st_row) * Kdim + k0 + st_c * 8,
               (char*)Bs + r * 4096 + wv * 1024);
  };

  const int nt = Kdim >> 6;
  for (int kt = 0; kt < nt; ++kt) {
    stage(kt << 6);
    __syncthreads();
    const char* Ap = (const char*)As;
    const char* Bp = (const char*)Bs;
#pragma unroll
    for (int ks = 0; ks < 4; ++ks) {
      const int csw = ((ks * 2 + hl) ^ (lq & 7)) * 16;
      const bf16x8 af = *reinterpret_cast<const bf16x8*>(
          Ap + (wm * 32 + lq) * 128 + csw);
#pragma unroll
      for (int j = 0; j < 2; ++j) {
        const bf16x8 bfr = *reinterpret_cast<const bf16x8*>(
            Bp + (wn * 64 + j * 32 + lq) * 128 + csw);
        acc[j] = __builtin_amdgcn_mfma_f32_32x32x16_bf16(af, bfr, acc[j], 0, 0, 0);
      }
    }
    __syncthreads();
  }

#pragma unroll
  for (int j = 0; j < 2; ++j) {
    const int gc = colBase + wn * 64 + j * 32 + lq;
    const float bv = bias[gc];
#pragma unroll
    for (int r = 0; r < 16; ++r) {
      const int gr = rowBase + wm * 32 + (r & 3) + 8 * (r >> 2) + 4 * hl;
      const float v = acc[j][r] + bv;
      if constexpr (EPI == 1) {
        outB[(size_t)gr * Ndim + gc] =
            __float2bfloat16(v + resF[(size_t)gr * Ndim + gc]);
      } else if constexpr (EPI == 2) {  // exact GELU
        outB[(size_t)gr * Ndim + gc] =
            __float2bfloat16(0.5f * v * (1.f + erff(v * 0.70710678118f)));
      } else {  // EPI == 3: f32 out + bf16 residual
        outF[(size_t)gr * Ndim + gc] =
            v + __bfloat162float(resB[(size_t)gr * Ndim + gc]);
      }
    }
  }
}

// ---------------- flash attention v5 (R12-verified): KVBLK=128, swapped
// 32x32x16 MFMA, in-register softmax, cvt_pk+permlane P path, XCD swizzle.
__global__ __launch_bounds__(256, 2) void attn_kernel(
    const __hip_bfloat16* __restrict__ q, const __hip_bfloat16* __restrict__ k,
    const __hip_bfloat16* __restrict__ vt, __hip_bfloat16* __restrict__ attn) {
  __shared__ alignas(16) __hip_bfloat16 Ks[2][128 * 64];  // [kv][d] 16 KB
  __shared__ alignas(16) __hip_bfloat16 Vs[2][64 * 128];  // [d][kv] 16 KB
  const int tid = threadIdx.x, wv = tid >> 6, ln = tid & 63;
  const int l = xcd_swz(blockIdx.x, gridDim.x);
  const int bh = l >> 3, qt = l & 7;
  const int b = bh >> 4, h = bh & 15;
  const int lq = ln & 31;
  const int hl = ln >> 5;

  const __hip_bfloat16* kbase = k + (size_t)bh * Nseq * HDd;
  const __hip_bfloat16* vbase = vt + (size_t)bh * HDd * Nseq;

  const int st_r = ln >> 3;
  const int st_c = (ln & 7) ^ st_r;
  const int sv_r = ln >> 4;
  const int sv_ci = ln & 15;

  const __hip_bfloat16* qsrc = q + ((size_t)bh * Nseq + qt * 128 + wv * 32 + lq) * HDd;
  bf16x8 qf[4];
#pragma unroll
  for (int s = 0; s < 4; ++s)
    qf[s] = *reinterpret_cast<const bf16x8*>(qsrc + s * 16 + hl * 8);

  float mrun = -1e30f, lrun = 0.f;
  f32x16 ot0 = {}, ot1 = {};

  auto stage = [&](int buf, int kt) {
#pragma unroll
    for (int c = 0; c < 4; ++c) {
      const int kc = wv * 4 + c;  // 0..15: 8 K-rows each
      gl_lds16(kbase + ((size_t)kt * 128 + kc * 8 + st_r) * HDd + st_c * 8,
               (char*)&Ks[buf][0] + kc * 1024);
      const int vr = kc * 4 + sv_r;  // d-row 0..63
      gl_lds16(vbase + (size_t)vr * Nseq + kt * 128 + (sv_ci ^ (vr & 7)) * 8,
               (char*)&Vs[buf][0] + kc * 1024);
    }
  };

  stage(0, 0);
  __syncthreads();
  int cur = 0;

  for (int kt = 0; kt < 8; ++kt) {
    if (kt < 7) stage(cur ^ 1, kt + 1);

    const char* Kp = (const char*)&Ks[cur][0];
    const char* Vp = (const char*)&Vs[cur][0];

    f32x16 st0 = {}, st1 = {}, st2 = {}, st3 = {};
#pragma unroll
    for (int t = 0; t < 4; ++t) {
      const int row = t * 32 + lq;
#pragma unroll
      for (int s = 0; s < 4; ++s) {
        const bf16x8 kf = *reinterpret_cast<const bf16x8*>(
            Kp + row * 128 + (((s * 2 + hl) ^ (row & 7)) * 16));
        if (t == 0)      st0 = __builtin_amdgcn_mfma_f32_32x32x16_bf16(kf, qf[s], st0, 0, 0, 0);
        else if (t == 1) st1 = __builtin_amdgcn_mfma_f32_32x32x16_bf16(kf, qf[s], st1, 0, 0, 0);
        else if (t == 2) st2 = __builtin_amdgcn_mfma_f32_32x32x16_bf16(kf, qf[s], st2, 0, 0, 0);
        else             st3 = __builtin_amdgcn_mfma_f32_32x32x16_bf16(kf, qf[s], st3, 0, 0, 0);
      }
    }

    float tmax = st0[0];
#pragma unroll
    for (int r = 1; r < 16; ++r) tmax = fmaxf(tmax, st0[r]);
#pragma unroll
    for (int r = 0; r < 16; ++r) tmax = fmaxf(tmax, st1[r]);
#pragma unroll
    for (int r = 0; r < 16; ++r) tmax = fmaxf(tmax, st2[r]);
#pragma unroll
    for (int r = 0; r < 16; ++r) tmax = fmaxf(tmax, st3[r]);
    tmax = fmaxf(tmax, __shfl_xor(tmax, 32));
    const float mn = fmaxf(mrun, tmax);
    const float sc = __expf(mrun - mn);
    mrun = mn;
    float tsum = 0.f;
#pragma unroll
    for (int r = 0; r < 16; ++r) { st0[r] = __expf(st0[r] - mn); tsum += st0[r]; }
#pragma unroll
    for (int r = 0; r < 16; ++r) { st1[r] = __expf(st1[r] - mn); tsum += st1[r]; }
#pragma unroll
    for (int r = 0; r < 16; ++r) { st2[r] = __expf(st2[r] - mn); tsum += st2[r]; }
#pragma unroll
    for (int r = 0; r < 16; ++r) { st3[r] = __expf(st3[r] - mn); tsum += st3[r]; }
    tsum += __shfl_xor(tsum, 32);
    lrun = lrun * sc + tsum;
#pragma unroll
    for (int r = 0; r < 16; ++r) { ot0[r] *= sc; ot1[r] *= sc; }

    union PF { unsigned u[4]; bf16x8 v; } pf[8];
#pragma unroll
    for (int t = 0; t < 4; ++t)
#pragma unroll
      for (int g = 0; g < 2; ++g) {
        float p0, p1, p2, p3, p4, p5, p6, p7;
        if (t == 0) { p0 = st0[g*8+0]; p1 = st0[g*8+1]; p2 = st0[g*8+2]; p3 = st0[g*8+3];
                      p4 = st0[g*8+4]; p5 = st0[g*8+5]; p6 = st0[g*8+6]; p7 = st0[g*8+7]; }
        else if (t == 1) { p0 = st1[g*8+0]; p1 = st1[g*8+1]; p2 = st1[g*8+2]; p3 = st1[g*8+3];
                           p4 = st1[g*8+4]; p5 = st1[g*8+5]; p6 = st1[g*8+6]; p7 = st1[g*8+7]; }
        else if (t == 2) { p0 = st2[g*8+0]; p1 = st2[g*8+1]; p2 = st2[g*8+2]; p3 = st2[g*8+3];
                           p4 = st2[g*8+4]; p5 = st2[g*8+5]; p6 = st2[g*8+6]; p7 = st2[g*8+7]; }
        else { p0 = st3[g*8+0]; p1 = st3[g*8+1]; p2 = st3[g*8+2]; p3 = st3[g*8+3];
               p4 = st3[g*8+4]; p5 = st3[g*8+5]; p6 = st3[g*8+6]; p7 = st3[g*8+7]; }
        unsigned w0 = cvt_pk_bf16(p0, p1);
        unsigned w1 = cvt_pk_bf16(p2, p3);
        unsigned w2 = cvt_pk_bf16(p4, p5);
        unsigned w3 = cvt_pk_bf16(p6, p7);
        pl32_swap(w0, w2);
        pl32_swap(w1, w3);
        PF f;
        f.u[0] = w0; f.u[1] = w1; f.u[2] = w2; f.u[3] = w3;
        pf[t * 2 + g] = f;
      }

#pragma unroll
    for (int dt = 0; dt < 2; ++dt) {
      const int row = dt * 32 + lq;
#pragma unroll
      for (int ks = 0; ks < 8; ++ks) {
        const bf16x8 vf = *reinterpret_cast<const bf16x8*>(
            Vp + row * 256 + (((ks * 2 + hl) ^ (row & 7)) * 16));
        if (dt == 0) ot0 = __builtin_amdgcn_mfma_f32_32x32x16_bf16(vf, pf[ks].v, ot0, 0, 0, 0);
        else         ot1 = __builtin_amdgcn_mfma_f32_32x32x16_bf16(vf, pf[ks].v, ot1, 0, 0, 0);
      }
    }

    __syncthreads();
    cur ^= 1;
  }

  const float inv = 1.f / lrun;
  char* swb = (char*)(&Ks[0][0] + wv * 2048);
#pragma unroll
  for (int dt = 0; dt < 2; ++dt)
#pragma unroll
    for (int i = 0; i < 8; ++i) {
      const unsigned w = (dt == 0)
          ? cvt_pk_bf16(ot0[2 * i] * inv, ot0[2 * i + 1] * inv)
          : cvt_pk_bf16(ot1[2 * i] * inv, ot1[2 * i + 1] * inv);
      const int d0 = (2 * i & 2) + 8 * (i >> 1) + 4 * hl + 32 * dt;
      *(unsigned*)(swb + lq * 128 + (((d0 >> 3) ^ (lq & 7)) * 16) + (d0 & 7) * 2) = w;
    }
  const int brow = b * Nseq + qt * 128 + wv * 32;
#pragma unroll
  for (int it = 0; it < 4; ++it) {
    const int qr = it * 8 + (ln >> 3);
    const bf16x8 o = *reinterpret_cast<const bf16x8*>(
        swb + qr * 128 + (((ln & 7) ^ (qr & 7)) * 16));
    *reinterpret_cast<bf16x8*>(attn + (size_t)(brow + qr) * Dm + h * 64 + (ln & 7) * 8) = o;
  }
}

extern "C" void kernel_launch(void* const* d_in, const int* in_sizes, int n_in,
                              void* d_out, int out_size, void* d_ws, size_t ws_size,
                              hipStream_t stream) {
  (void)in_sizes; (void)n_in; (void)out_size; (void)ws_size;
  const float* x     = (const float*)d_in[0];
  const float* ln1_g = (const float*)d_in[1];
  const float* ln1_b = (const float*)d_in[2];
  const float* qkv_w = (const float*)d_in[3];
  const float* qkv_b = (const float*)d_in[4];
  const float* out_w = (const float*)d_in[5];
  const float* out_b = (const float*)d_in[6];
  const float* ln2_g = (const float*)d_in[7];
  const float* ln2_b = (const float*)d_in[8];
  const float* w1    = (const float*)d_in[9];
  const float* b1    = (const float*)d_in[10];
  const float* w2    = (const float*)d_in[11];
  const float* b2    = (const float*)d_in[12];
  float* outp = (float*)d_out;

  char* ws = (char*)d_ws;
  size_t off = 0;
  auto take = [&](size_t bytes) {
    char* p = ws + off;
    off += (bytes + 255) & ~(size_t)255;
    return p;
  };
  __hip_bfloat16* wqkv_t = (__hip_bfloat16*)take((size_t)3 * Dm * Dm * 2);
  __hip_bfloat16* wout_t = (__hip_bfloat16*)take((size_t)Dm * Dm * 2);
  __hip_bfloat16* w1_t   = (__hip_bfloat16*)take((size_t)FFd * Dm * 2);
  __hip_bfloat16* w2_t   = (__hip_bfloat16*)take((size_t)Dm * FFd * 2);
  __hip_bfloat16* xn     = (__hip_bfloat16*)take((size_t)Mrows * Dm * 2);  // reused as LN2 out
  __hip_bfloat16* qb     = (__hip_bfloat16*)take((size_t)Mrows * Dm * 2);
  __hip_bfloat16* kb     = (__hip_bfloat16*)take((size_t)Mrows * Dm * 2);
  __hip_bfloat16* vtb    = (__hip_bfloat16*)take((size_t)Mrows * Dm * 2);
  __hip_bfloat16* attn   = (__hip_bfloat16*)take((size_t)Mrows * Dm * 2);
  __hip_bfloat16* x1b    = (__hip_bfloat16*)take((size_t)Mrows * Dm * 2);  // bf16 residual
  __hip_bfloat16* gbuf   = (__hip_bfloat16*)take((size_t)Mrows * FFd * 2);

  const dim3 blk(256);
  // fused prologue: 4 weight transposes + LN1 (independent; one dispatch)
  prep_kernel<<<dim3(12288), blk, 0, stream>>>(
      qkv_w, wqkv_t, out_w, wout_t, w1, w1_t, w2, w2_t, x, ln1_g, ln1_b, xn);
  // QKV projection (counted-vmcnt dbuf), scatter q/k/v^T
  gemm_qkv<<<dim3(3 * Dm / 128, Mrows / 128), blk, 0, stream>>>(
      xn, wqkv_t, qkv_b, qb, kb, vtb, 3 * Dm, Dm);
  // attention (swapped 32x32 MFMA, KVBLK=128): 64 bh x 8 q-tiles of 128 rows
  attn_kernel<<<dim3(Bq * Hh * (Nseq / 128)), blk, 0, stream>>>(qb, kb, vtb, attn);
  // output projection + residual -> x1b (bf16): skinny 64x128 (512 blocks)
  gemm_sk<1><<<dim3(Dm / 128, Mrows / 64), blk, 0, stream>>>(
      attn, wout_t, out_b, x, nullptr, nullptr, x1b, Dm, Dm);
  // LN2 over bf16 x1
  ln_bf16_kernel<<<dim3(Mrows), blk, 0, stream>>>(x1b, ln2_g, ln2_b, xn);
  // FFN1 + GELU -> gbuf (bf16): skinny 64x128 (1024 blocks = 4/CU)
  gemm_sk<2><<<dim3(FFd / 128, Mrows / 64), blk, 0, stream>>>(
      xn, w1_t, b1, nullptr, nullptr, nullptr, gbuf, FFd, Dm);
  // FFN2 + bf16 residual -> out (f32): skinny 64x128 (512 blocks)
  gemm_sk<3><<<dim3(Dm / 128, Mrows / 64), blk, 0, stream>>>(
      gbuf, w2_t, b2, nullptr, x1b, outp, nullptr, Dm, FFd);
}

// Round 15
// 166.243 us; speedup vs baseline: 1.0269x; 1.0269x over previous
//
#include <hip/hip_runtime.h>
#include <hip/hip_bf16.h>
#include <cstdint>
#include <cstddef>

// Shapes (compile-time)
#define Bq 4
#define Nseq 1024
#define Dm 1024
#define Hh 16
#define HDd 64
#define FFd 2048
#define Mrows 4096  // B*N

typedef __attribute__((ext_vector_type(8))) short bf16x8;   // 8 bf16 = 4 VGPRs
typedef __attribute__((ext_vector_type(4))) float f32x4;
typedef __attribute__((ext_vector_type(16))) float f32x16;

__device__ __forceinline__ void gl_lds16(const void* g, void* l) {
  // async global->LDS, 16B per lane; LDS dest = wave-uniform base + lane*16
  __builtin_amdgcn_global_load_lds(
      (const __attribute__((address_space(1))) unsigned int*)g,
      (__attribute__((address_space(3))) unsigned int*)l, 16, 0, 0);
}

__device__ __forceinline__ unsigned short f2b(float f) {
  union { __hip_bfloat16 h; unsigned short u; } cv;
  cv.h = __float2bfloat16(f);
  return cv.u;
}

__device__ __forceinline__ unsigned cvt_pk_bf16(float a, float b) {
  unsigned r;
  asm("v_cvt_pk_bf16_f32 %0, %1, %2" : "=v"(r) : "v"(a), "v"(b));
  return r;  // low16 = bf16(a), high16 = bf16(b)
}

__device__ __forceinline__ void pl32_swap(unsigned& a, unsigned& b) {
  asm("v_permlane32_swap_b32 %0, %1" : "+v"(a), "+v"(b));
}

// XCD-chunked swizzle (T1): dispatch index d -> logical block l such that each
// XCD (d%8) owns a CONTIGUOUS logical chunk. Requires nwg % 8 == 0.
__device__ __forceinline__ int xcd_swz(int d, int nwg) {
  return (d & 7) * (nwg >> 3) + (d >> 3);
}

// ---------------- prep kernel: 4 weight transposes + LN1 fused in one dispatch
__device__ __forceinline__ void tr_tile(const float* __restrict__ src,
                                        __hip_bfloat16* __restrict__ dst,
                                        int K, int Ncols, int n0, int k0,
                                        int tid) {
  __shared__ float tile[32][33];
  const int tx = tid & 31, ty = tid >> 5;  // ty 0..7
#pragma unroll
  for (int i = 0; i < 32; i += 8)
    tile[ty + i][tx] = src[(size_t)(k0 + ty + i) * Ncols + n0 + tx];
  __syncthreads();
#pragma unroll
  for (int i = 0; i < 32; i += 8)
    dst[(size_t)(n0 + ty + i) * K + k0 + tx] = __float2bfloat16(tile[tx][ty + i]);
}

__global__ __launch_bounds__(256) void prep_kernel(
    const float* __restrict__ qkv_w, __hip_bfloat16* __restrict__ wqkv_t,
    const float* __restrict__ out_w, __hip_bfloat16* __restrict__ wout_t,
    const float* __restrict__ w1, __hip_bfloat16* __restrict__ w1_t,
    const float* __restrict__ w2, __hip_bfloat16* __restrict__ w2_t,
    const float* __restrict__ x, const float* __restrict__ ln1_g,
    const float* __restrict__ ln1_b, __hip_bfloat16* __restrict__ xn) {
  const int id = blockIdx.x, tid = threadIdx.x;
  if (id < 3072) {
    tr_tile(qkv_w, wqkv_t, Dm, 3 * Dm, (id % 96) * 32, (id / 96) * 32, tid);
  } else if (id < 4096) {
    const int i2 = id - 3072;
    tr_tile(out_w, wout_t, Dm, Dm, (i2 % 32) * 32, (i2 / 32) * 32, tid);
  } else if (id < 6144) {
    const int i2 = id - 4096;
    tr_tile(w1, w1_t, Dm, FFd, (i2 % 64) * 32, (i2 / 64) * 32, tid);
  } else if (id < 8192) {
    const int i2 = id - 6144;
    tr_tile(w2, w2_t, FFd, Dm, (i2 % 32) * 32, (i2 / 32) * 32, tid);
  } else {
    const int row = id - 8192;
    const float4 v = reinterpret_cast<const float4*>(x + (size_t)row * Dm)[tid];
    float s1 = v.x + v.y + v.z + v.w;
    float s2 = v.x * v.x + v.y * v.y + v.z * v.z + v.w * v.w;
#pragma unroll
    for (int m = 1; m < 64; m <<= 1) {
      s1 += __shfl_xor(s1, m);
      s2 += __shfl_xor(s2, m);
    }
    __shared__ float a1[4], a2[4];
    const int wv = tid >> 6;
    if ((tid & 63) == 0) { a1[wv] = s1; a2[wv] = s2; }
    __syncthreads();
    s1 = a1[0] + a1[1] + a1[2] + a1[3];
    s2 = a2[0] + a2[1] + a2[2] + a2[3];
    const float mu = s1 * (1.f / Dm);
    const float rs = rsqrtf(s2 * (1.f / Dm) - mu * mu + 1e-5f);
    const float4 g4 = reinterpret_cast<const float4*>(ln1_g)[tid];
    const float4 b4 = reinterpret_cast<const float4*>(ln1_b)[tid];
    ushort4 o;
    o.x = f2b((v.x - mu) * rs * g4.x + b4.x);
    o.y = f2b((v.y - mu) * rs * g4.y + b4.y);
    o.z = f2b((v.z - mu) * rs * g4.z + b4.z);
    o.w = f2b((v.w - mu) * rs * g4.w + b4.w);
    reinterpret_cast<ushort4*>(xn + (size_t)row * Dm)[tid] = o;
  }
}

// ---------------- layernorm over bf16 input: [4096][1024] row -> bf16 out (LN2)
__global__ __launch_bounds__(256) void ln_bf16_kernel(
    const __hip_bfloat16* __restrict__ xb, const float* __restrict__ gw,
    const float* __restrict__ bw, __hip_bfloat16* __restrict__ out) {
  const int row = blockIdx.x;
  const ushort4 u = reinterpret_cast<const ushort4*>(xb + (size_t)row * Dm)[threadIdx.x];
  union { __hip_bfloat16 h; unsigned short s; } c0{{}}, c1{{}}, c2{{}}, c3{{}};
  c0.s = u.x; c1.s = u.y; c2.s = u.z; c3.s = u.w;
  float vx = __bfloat162float(c0.h), vy = __bfloat162float(c1.h);
  float vz = __bfloat162float(c2.h), vw = __bfloat162float(c3.h);
  float s1 = vx + vy + vz + vw;
  float s2 = vx * vx + vy * vy + vz * vz + vw * vw;
#pragma unroll
  for (int m = 1; m < 64; m <<= 1) {
    s1 += __shfl_xor(s1, m);
    s2 += __shfl_xor(s2, m);
  }
  __shared__ float a1[4], a2[4];
  const int wv = threadIdx.x >> 6;
  if ((threadIdx.x & 63) == 0) { a1[wv] = s1; a2[wv] = s2; }
  __syncthreads();
  s1 = a1[0] + a1[1] + a1[2] + a1[3];
  s2 = a2[0] + a2[1] + a2[2] + a2[3];
  const float mu = s1 * (1.f / Dm);
  const float rs = rsqrtf(s2 * (1.f / Dm) - mu * mu + 1e-5f);
  const float4 g4 = reinterpret_cast<const float4*>(gw)[threadIdx.x];
  const float4 b4 = reinterpret_cast<const float4*>(bw)[threadIdx.x];
  ushort4 o;
  o.x = f2b((vx - mu) * rs * g4.x + b4.x);
  o.y = f2b((vy - mu) * rs * g4.y + b4.y);
  o.z = f2b((vz - mu) * rs * g4.z + b4.z);
  o.w = f2b((vw - mu) * rs * g4.w + b4.w);
  reinterpret_cast<ushort4*>(out + (size_t)row * Dm)[threadIdx.x] = o;
}

// ---------------- GEMM (R7-verified): 128x128 tile, BK=64, single-buffer
// (32 KB LDS), 32x32x16 MFMA, 2 __syncthreads/iter, XCD-chunked swizzle.
// (Best measured of 10 schedule variants: R4-R8, R13, R14 all bracketed
//  46-89 us; this structure is the floor at 46.4 us.)
__global__ __launch_bounds__(256, 3) void gemm_qkv(
    const __hip_bfloat16* __restrict__ A, const __hip_bfloat16* __restrict__ BT,
    const float* __restrict__ bias,
    __hip_bfloat16* __restrict__ qb, __hip_bfloat16* __restrict__ kb,
    __hip_bfloat16* __restrict__ vtb, int Ndim, int Kdim) {
  __shared__ alignas(16) __hip_bfloat16 As[128 * 64];  // 16 KB
  __shared__ alignas(16) __hip_bfloat16 Bs[128 * 64];  // 16 KB
  const int tid = threadIdx.x;
  const int wv = tid >> 6, ln = tid & 63;
  const int wm = wv >> 1, wn = wv & 1;
  const int lq = ln & 31, hl = ln >> 5;
  const int gx = gridDim.x;
  const int l = xcd_swz(blockIdx.x + gx * blockIdx.y, gx * gridDim.y);
  const int rowBase = (l / gx) * 128;
  const int colBase = (l % gx) * 128;

  const int st_row = tid >> 3;                 // 0..31 within round
  const int st_c = (tid & 7) ^ (st_row & 7);   // swizzled 16B-chunk index

  f32x16 acc[2][2];
#pragma unroll
  for (int i = 0; i < 2; ++i)
#pragma unroll
    for (int j = 0; j < 2; ++j) acc[i][j] = {};

  auto stage = [&](int k0) {
#pragma unroll
    for (int r = 0; r < 4; ++r) {
      gl_lds16(A + (size_t)(rowBase + r * 32 + st_row) * Kdim + k0 + st_c * 8,
               (char*)As + r * 4096 + wv * 1024);
      gl_lds16(BT + (size_t)(colBase + r * 32 + st_row) * Kdim + k0 + st_c * 8,
               (char*)Bs + r * 4096 + wv * 1024);
    }
  };

  const int nt = Kdim >> 6;
  for (int kt = 0; kt < nt; ++kt) {
    stage(kt << 6);
    __syncthreads();
    const char* Ap = (const char*)As;
    const char* Bp = (const char*)Bs;
#pragma unroll
    for (int ks = 0; ks < 4; ++ks) {
      bf16x8 af[2], bfr[2];
#pragma unroll
      for (int i = 0; i < 2; ++i)
        af[i] = *reinterpret_cast<const bf16x8*>(
            Ap + (wm * 64 + i * 32 + lq) * 128 + (((ks * 2 + hl) ^ (lq & 7)) * 16));
#pragma unroll
      for (int j = 0; j < 2; ++j)
        bfr[j] = *reinterpret_cast<const bf16x8*>(
            Bp + (wn * 64 + j * 32 + lq) * 128 + (((ks * 2 + hl) ^ (lq & 7)) * 16));
#pragma unroll
      for (int i = 0; i < 2; ++i)
#pragma unroll
        for (int j = 0; j < 2; ++j)
          acc[i][j] = __builtin_amdgcn_mfma_f32_32x32x16_bf16(af[i], bfr[j], acc[i][j], 0, 0, 0);
    }
    __syncthreads();
  }

  // epilogue: 32x32 C/D layout: col = lq, row = (r&3) + 8*(r>>2) + 4*hl
#pragma unroll
  for (int i = 0; i < 2; ++i) {
#pragma unroll
    for (int j = 0; j < 2; ++j) {
      const int gc = colBase + wn * 64 + j * 32 + lq;
      const float bv = bias[gc];
#pragma unroll
      for (int r = 0; r < 16; ++r) {
        const int gr = rowBase + wm * 64 + i * 32 + (r & 3) + 8 * (r >> 2) + 4 * hl;
        float v = acc[i][j][r] + bv;
        const int which = gc >> 10;
        const int dcol = gc & 1023;
        const int h = dcol >> 6, hd = dcol & 63;
        const int b = gr >> 10, n = gr & 1023;
        const size_t bh = (size_t)(b * Hh + h);
        if (which == 0)
          qb[(bh * Nseq + n) * HDd + hd] = __float2bfloat16(v * 0.125f);
        else if (which == 1)
          kb[(bh * Nseq + n) * HDd + hd] = __float2bfloat16(v);
        else
          vtb[(bh * HDd + hd) * Nseq + n] = __float2bfloat16(v);
      }
    }
  }
}

// ---------------- skinny GEMM: 64x128 tile, 4 waves 2M x 2N, per-wave 32x64,
// BK=64 single-buffer, 24 KB LDS, XCD-chunked swizzle.
// EPI 1: bf16 out = bf16(acc + bias + resF)   (outproj residual; x1 bf16)
// EPI 2: bf16 out = gelu(acc + bias)
// EPI 3: f32 out = acc + bias + float(resB)   (FFN2 residual from bf16 x1)
template <int EPI>
__global__ __launch_bounds__(256, 4) void gemm_sk(
    const __hip_bfloat16* __restrict__ A, const __hip_bfloat16* __restrict__ BT,
    const float* __restrict__ bias, const float* __restrict__ resF,
    const __hip_bfloat16* __restrict__ resB,
    float* __restrict__ outF, __hip_bfloat16* __restrict__ outB,
    int Ndim, int Kdim) {
  __shared__ alignas(16) __hip_bfloat16 As[64 * 64];    // 8 KB
  __shared__ alignas(16) __hip_bfloat16 Bs[128 * 64];   // 16 KB
  const int tid = threadIdx.x;
  const int wv = tid >> 6, ln = tid & 63;
  const int wm = wv >> 1, wn = wv & 1;
  const int lq = ln & 31, hl = ln >> 5;
  const int gx = gridDim.x;
  const int l = xcd_swz(blockIdx.x + gx * blockIdx.y, gx * gridDim.y);
  const int rowBase = (l / gx) * 64;
  const int colBase = (l % gx) * 128;

  const int st_row = tid >> 3;
  const int st_c = (tid & 7) ^ (st_row & 7);

  f32x16 acc[2];
  acc[0] = {}; acc[1] = {};

  auto stage = [&](int k0) {
#pragma unroll
    for (int r = 0; r < 2; ++r)
      gl_lds16(A + (size_t)(rowBase + r * 32 + st_row) * Kdim + k0 + st_c * 8,
               (char*)As + r * 4096 + wv * 1024);
#pragma unroll
    for (int r = 0; r < 4; ++r)
      gl_lds16(BT + (size_t)(colBase + r * 32 + st_row) * Kdim + k0 + st_c * 8,
               (char*)Bs + r * 4096 + wv * 1024);
  };

  const int nt = Kdim >> 6;
  for (int kt = 0; kt < nt; ++kt) {
    stage(kt << 6);
    __syncthreads();
    const char* Ap = (const char*)As;
    const char* Bp = (const char*)Bs;
#pragma unroll
    for (int ks = 0; ks < 4; ++ks) {
      const int csw = ((ks * 2 + hl) ^ (lq & 7)) * 16;
      const bf16x8 af = *reinterpret_cast<const bf16x8*>(
          Ap + (wm * 32 + lq) * 128 + csw);
#pragma unroll
      for (int j = 0; j < 2; ++j) {
        const bf16x8 bfr = *reinterpret_cast<const bf16x8*>(
            Bp + (wn * 64 + j * 32 + lq) * 128 + csw);
        acc[j] = __builtin_amdgcn_mfma_f32_32x32x16_bf16(af, bfr, acc[j], 0, 0, 0);
      }
    }
    __syncthreads();
  }

#pragma unroll
  for (int j = 0; j < 2; ++j) {
    const int gc = colBase + wn * 64 + j * 32 + lq;
    const float bv = bias[gc];
#pragma unroll
    for (int r = 0; r < 16; ++r) {
      const int gr = rowBase + wm * 32 + (r & 3) + 8 * (r >> 2) + 4 * hl;
      const float v = acc[j][r] + bv;
      if constexpr (EPI == 1) {
        outB[(size_t)gr * Ndim + gc] =
            __float2bfloat16(v + resF[(size_t)gr * Ndim + gc]);
      } else if constexpr (EPI == 2) {  // exact GELU
        outB[(size_t)gr * Ndim + gc] =
            __float2bfloat16(0.5f * v * (1.f + erff(v * 0.70710678118f)));
      } else {  // EPI == 3: f32 out + bf16 residual
        outF[(size_t)gr * Ndim + gc] =
            v + __bfloat162float(resB[(size_t)gr * Ndim + gc]);
      }
    }
  }
}

// ---------------- flash attention v5 (R12-verified): KVBLK=128, swapped
// 32x32x16 MFMA, in-register softmax, cvt_pk+permlane P path, XCD swizzle.
__global__ __launch_bounds__(256, 2) void attn_kernel(
    const __hip_bfloat16* __restrict__ q, const __hip_bfloat16* __restrict__ k,
    const __hip_bfloat16* __restrict__ vt, __hip_bfloat16* __restrict__ attn) {
  __shared__ alignas(16) __hip_bfloat16 Ks[2][128 * 64];  // [kv][d] 16 KB
  __shared__ alignas(16) __hip_bfloat16 Vs[2][64 * 128];  // [d][kv] 16 KB
  const int tid = threadIdx.x, wv = tid >> 6, ln = tid & 63;
  const int l = xcd_swz(blockIdx.x, gridDim.x);
  const int bh = l >> 3, qt = l & 7;
  const int b = bh >> 4, h = bh & 15;
  const int lq = ln & 31;
  const int hl = ln >> 5;

  const __hip_bfloat16* kbase = k + (size_t)bh * Nseq * HDd;
  const __hip_bfloat16* vbase = vt + (size_t)bh * HDd * Nseq;

  const int st_r = ln >> 3;
  const int st_c = (ln & 7) ^ st_r;
  const int sv_r = ln >> 4;
  const int sv_ci = ln & 15;

  const __hip_bfloat16* qsrc = q + ((size_t)bh * Nseq + qt * 128 + wv * 32 + lq) * HDd;
  bf16x8 qf[4];
#pragma unroll
  for (int s = 0; s < 4; ++s)
    qf[s] = *reinterpret_cast<const bf16x8*>(qsrc + s * 16 + hl * 8);

  float mrun = -1e30f, lrun = 0.f;
  f32x16 ot0 = {}, ot1 = {};

  auto stage = [&](int buf, int kt) {
#pragma unroll
    for (int c = 0; c < 4; ++c) {
      const int kc = wv * 4 + c;  // 0..15: 8 K-rows each
      gl_lds16(kbase + ((size_t)kt * 128 + kc * 8 + st_r) * HDd + st_c * 8,
               (char*)&Ks[buf][0] + kc * 1024);
      const int vr = kc * 4 + sv_r;  // d-row 0..63
      gl_lds16(vbase + (size_t)vr * Nseq + kt * 128 + (sv_ci ^ (vr & 7)) * 8,
               (char*)&Vs[buf][0] + kc * 1024);
    }
  };

  stage(0, 0);
  __syncthreads();
  int cur = 0;

  for (int kt = 0; kt < 8; ++kt) {
    if (kt < 7) stage(cur ^ 1, kt + 1);

    const char* Kp = (const char*)&Ks[cur][0];
    const char* Vp = (const char*)&Vs[cur][0];

    f32x16 st0 = {}, st1 = {}, st2 = {}, st3 = {};
#pragma unroll
    for (int t = 0; t < 4; ++t) {
      const int row = t * 32 + lq;
#pragma unroll
      for (int s = 0; s < 4; ++s) {
        const bf16x8 kf = *reinterpret_cast<const bf16x8*>(
            Kp + row * 128 + (((s * 2 + hl) ^ (row & 7)) * 16));
        if (t == 0)      st0 = __builtin_amdgcn_mfma_f32_32x32x16_bf16(kf, qf[s], st0, 0, 0, 0);
        else if (t == 1) st1 = __builtin_amdgcn_mfma_f32_32x32x16_bf16(kf, qf[s], st1, 0, 0, 0);
        else if (t == 2) st2 = __builtin_amdgcn_mfma_f32_32x32x16_bf16(kf, qf[s], st2, 0, 0, 0);
        else             st3 = __builtin_amdgcn_mfma_f32_32x32x16_bf16(kf, qf[s], st3, 0, 0, 0);
      }
    }

    float tmax = st0[0];
#pragma unroll
    for (int r = 1; r < 16; ++r) tmax = fmaxf(tmax, st0[r]);
#pragma unroll
    for (int r = 0; r < 16; ++r) tmax = fmaxf(tmax, st1[r]);
#pragma unroll
    for (int r = 0; r < 16; ++r) tmax = fmaxf(tmax, st2[r]);
#pragma unroll
    for (int r = 0; r < 16; ++r) tmax = fmaxf(tmax, st3[r]);
    tmax = fmaxf(tmax, __shfl_xor(tmax, 32));
    const float mn = fmaxf(mrun, tmax);
    const float sc = __expf(mrun - mn);
    mrun = mn;
    float tsum = 0.f;
#pragma unroll
    for (int r = 0; r < 16; ++r) { st0[r] = __expf(st0[r] - mn); tsum += st0[r]; }
#pragma unroll
    for (int r = 0; r < 16; ++r) { st1[r] = __expf(st1[r] - mn); tsum += st1[r]; }
#pragma unroll
    for (int r = 0; r < 16; ++r) { st2[r] = __expf(st2[r] - mn); tsum += st2[r]; }
#pragma unroll
    for (int r = 0; r < 16; ++r) { st3[r] = __expf(st3[r] - mn); tsum += st3[r]; }
    tsum += __shfl_xor(tsum, 32);
    lrun = lrun * sc + tsum;
#pragma unroll
    for (int r = 0; r < 16; ++r) { ot0[r] *= sc; ot1[r] *= sc; }

    union PF { unsigned u[4]; bf16x8 v; } pf[8];
#pragma unroll
    for (int t = 0; t < 4; ++t)
#pragma unroll
      for (int g = 0; g < 2; ++g) {
        float p0, p1, p2, p3, p4, p5, p6, p7;
        if (t == 0) { p0 = st0[g*8+0]; p1 = st0[g*8+1]; p2 = st0[g*8+2]; p3 = st0[g*8+3];
                      p4 = st0[g*8+4]; p5 = st0[g*8+5]; p6 = st0[g*8+6]; p7 = st0[g*8+7]; }
        else if (t == 1) { p0 = st1[g*8+0]; p1 = st1[g*8+1]; p2 = st1[g*8+2]; p3 = st1[g*8+3];
                           p4 = st1[g*8+4]; p5 = st1[g*8+5]; p6 = st1[g*8+6]; p7 = st1[g*8+7]; }
        else if (t == 2) { p0 = st2[g*8+0]; p1 = st2[g*8+1]; p2 = st2[g*8+2]; p3 = st2[g*8+3];
                           p4 = st2[g*8+4]; p5 = st2[g*8+5]; p6 = st2[g*8+6]; p7 = st2[g*8+7]; }
        else { p0 = st3[g*8+0]; p1 = st3[g*8+1]; p2 = st3[g*8+2]; p3 = st3[g*8+3];
               p4 = st3[g*8+4]; p5 = st3[g*8+5]; p6 = st3[g*8+6]; p7 = st3[g*8+7]; }
        unsigned w0 = cvt_pk_bf16(p0, p1);
        unsigned w1 = cvt_pk_bf16(p2, p3);
        unsigned w2 = cvt_pk_bf16(p4, p5);
        unsigned w3 = cvt_pk_bf16(p6, p7);
        pl32_swap(w0, w2);
        pl32_swap(w1, w3);
        PF f;
        f.u[0] = w0; f.u[1] = w1; f.u[2] = w2; f.u[3] = w3;
        pf[t * 2 + g] = f;
      }

#pragma unroll
    for (int dt = 0; dt < 2; ++dt) {
      const int row = dt * 32 + lq;
#pragma unroll
      for (int ks = 0; ks < 8; ++ks) {
        const bf16x8 vf = *reinterpret_cast<const bf16x8*>(
            Vp + row * 256 + (((ks * 2 + hl) ^ (row & 7)) * 16));
        if (dt == 0) ot0 = __builtin_amdgcn_mfma_f32_32x32x16_bf16(vf, pf[ks].v, ot0, 0, 0, 0);
        else         ot1 = __builtin_amdgcn_mfma_f32_32x32x16_bf16(vf, pf[ks].v, ot1, 0, 0, 0);
      }
    }

    __syncthreads();
    cur ^= 1;
  }

  const float inv = 1.f / lrun;
  char* swb = (char*)(&Ks[0][0] + wv * 2048);
#pragma unroll
  for (int dt = 0; dt < 2; ++dt)
#pragma unroll
    for (int i = 0; i < 8; ++i) {
      const unsigned w = (dt == 0)
          ? cvt_pk_bf16(ot0[2 * i] * inv, ot0[2 * i + 1] * inv)
          : cvt_pk_bf16(ot1[2 * i] * inv, ot1[2 * i + 1] * inv);
      const int d0 = (2 * i & 2) + 8 * (i >> 1) + 4 * hl + 32 * dt;
      *(unsigned*)(swb + lq * 128 + (((d0 >> 3) ^ (lq & 7)) * 16) + (d0 & 7) * 2) = w;
    }
  const int brow = b * Nseq + qt * 128 + wv * 32;
#pragma unroll
  for (int it = 0; it < 4; ++it) {
    const int qr = it * 8 + (ln >> 3);
    const bf16x8 o = *reinterpret_cast<const bf16x8*>(
        swb + qr * 128 + (((ln & 7) ^ (qr & 7)) * 16));
    *reinterpret_cast<bf16x8*>(attn + (size_t)(brow + qr) * Dm + h * 64 + (ln & 7) * 8) = o;
  }
}

extern "C" void kernel_launch(void* const* d_in, const int* in_sizes, int n_in,
                              void* d_out, int out_size, void* d_ws, size_t ws_size,
                              hipStream_t stream) {
  (void)in_sizes; (void)n_in; (void)out_size; (void)ws_size;
  const float* x     = (const float*)d_in[0];
  const float* ln1_g = (const float*)d_in[1];
  const float* ln1_b = (const float*)d_in[2];
  const float* qkv_w = (const float*)d_in[3];
  const float* qkv_b = (const float*)d_in[4];
  const float* out_w = (const float*)d_in[5];
  const float* out_b = (const float*)d_in[6];
  const float* ln2_g = (const float*)d_in[7];
  const float* ln2_b = (const float*)d_in[8];
  const float* w1    = (const float*)d_in[9];
  const float* b1    = (const float*)d_in[10];
  const float* w2    = (const float*)d_in[11];
  const float* b2    = (const float*)d_in[12];
  float* outp = (float*)d_out;

  char* ws = (char*)d_ws;
  size_t off = 0;
  auto take = [&](size_t bytes) {
    char* p = ws + off;
    off += (bytes + 255) & ~(size_t)255;
    return p;
  };
  __hip_bfloat16* wqkv_t = (__hip_bfloat16*)take((size_t)3 * Dm * Dm * 2);
  __hip_bfloat16* wout_t = (__hip_bfloat16*)take((size_t)Dm * Dm * 2);
  __hip_bfloat16* w1_t   = (__hip_bfloat16*)take((size_t)FFd * Dm * 2);
  __hip_bfloat16* w2_t   = (__hip_bfloat16*)take((size_t)Dm * FFd * 2);
  __hip_bfloat16* xn     = (__hip_bfloat16*)take((size_t)Mrows * Dm * 2);  // reused as LN2 out
  __hip_bfloat16* qb     = (__hip_bfloat16*)take((size_t)Mrows * Dm * 2);
  __hip_bfloat16* kb     = (__hip_bfloat16*)take((size_t)Mrows * Dm * 2);
  __hip_bfloat16* vtb    = (__hip_bfloat16*)take((size_t)Mrows * Dm * 2);
  __hip_bfloat16* attn   = (__hip_bfloat16*)take((size_t)Mrows * Dm * 2);
  __hip_bfloat16* x1b    = (__hip_bfloat16*)take((size_t)Mrows * Dm * 2);  // bf16 residual
  __hip_bfloat16* gbuf   = (__hip_bfloat16*)take((size_t)Mrows * FFd * 2);

  const dim3 blk(256);
  // fused prologue: 4 weight transposes + LN1 (independent; one dispatch)
  prep_kernel<<<dim3(12288), blk, 0, stream>>>(
      qkv_w, wqkv_t, out_w, wout_t, w1, w1_t, w2, w2_t, x, ln1_g, ln1_b, xn);
  // QKV projection, scatter q/k/v^T
  gemm_qkv<<<dim3(3 * Dm / 128, Mrows / 128), blk, 0, stream>>>(
      xn, wqkv_t, qkv_b, qb, kb, vtb, 3 * Dm, Dm);
  // attention (swapped 32x32 MFMA, KVBLK=128): 64 bh x 8 q-tiles of 128 rows
  attn_kernel<<<dim3(Bq * Hh * (Nseq / 128)), blk, 0, stream>>>(qb, kb, vtb, attn);
  // output projection + residual -> x1b (bf16): skinny 64x128 (512 blocks)
  gemm_sk<1><<<dim3(Dm / 128, Mrows / 64), blk, 0, stream>>>(
      attn, wout_t, out_b, x, nullptr, nullptr, x1b, Dm, Dm);
  // LN2 over bf16 x1
  ln_bf16_kernel<<<dim3(Mrows), blk, 0, stream>>>(x1b, ln2_g, ln2_b, xn);
  // FFN1 + GELU -> gbuf (bf16): skinny 64x128 (1024 blocks = 4/CU)
  gemm_sk<2><<<dim3(FFd / 128, Mrows / 64), blk, 0, stream>>>(
      xn, w1_t, b1, nullptr, nullptr, nullptr, gbuf, FFd, Dm);
  // FFN2 + bf16 residual -> out (f32): skinny 64x128 (512 blocks)
  gemm_sk<3><<<dim3(Dm / 128, Mrows / 64), blk, 0, stream>>>(
      gbuf, w2_t, b2, nullptr, x1b, outp, nullptr, Dm, FFd);
}